// Round 12
// baseline (777.034 us; speedup 1.0000x reference)
//
#include <hip/hip_runtime.h>
#include <cstddef>

// LSTM T=2048, B=2048, I=1, H=20; gates [f,i,o,c] rows of W/U.
// Round-12: register-only h exchange using ONLY textbook DPP ops
// (quad_perm xor1/xor2, row_half_mirror=xor7, row_mirror=xor15) — no
// permlane32, no LDS h-traffic, no barriers, no cross-row movement.
//  - wave = 4 rows x 16 lanes = 4 batches. Lane (row,i) computes TWO units
//    in an f2: .x = unit i, .y = unit 16+(i&3) (4x replicated in-row, so
//    the extra-4 h values are available IN-QUAD).
//  - butterfly: hx[q] (15 movs) = h[i^M[q]], M={0,1,2,3,7,6,5,4,15,14,13,
//    12,8,9,10,11}; hy[q] (3 movs) = h[16+((i^q)&3)], q=0..3.
//  - weights pre-permuted to match butterfly order and pre-scaled
//    (-log2e for f,i,o; +2log2e for c): acts = rcp(1+exp2(z)), c scaled
//    by 2log2e (r4-proven algebra).
//  - dot per gate: one f2 chain (units x,y together): 16 pk_fma main +
//    4 pk_fma extra + bias + w*x, split in 2 partials.
//  - x: r4-proven LDS chunk staging (16 steps), register-prefetched.
// Grid 512 one-wave blocks; wall = T x per-wave issue (~350 cyc, 4 batches).

constexpr int T = 2048;
constexpr int B = 2048;
constexpr int H = 20;
constexpr int CHUNK = 16;
constexpr int NCH = T / CHUNK;      // 128 exact

typedef float f2 __attribute__((ext_vector_type(2)));

__device__ __forceinline__ float rcp_f(float v) { return __builtin_amdgcn_rcpf(v); }
__device__ __forceinline__ float ex2(float v)   { return __builtin_amdgcn_exp2f(v); }
template <int CTRL>
__device__ __forceinline__ float dpp_f(float v) {
  return __int_as_float(__builtin_amdgcn_update_dpp(
      0, __float_as_int(v), CTRL, 0xF, 0xF, true));
}
__device__ __forceinline__ f2 dup(float v) { f2 r; r.x = v; r.y = v; return r; }
// DPP ctrl: quad_perm[1,0,3,2]=0xB1 (xor1), [2,3,0,1]=0x4E (xor2),
// row_half_mirror=0x141 (xor7), row_mirror=0x140 (xor15).

__global__ __launch_bounds__(64, 1)
void lstm_qb(const float* __restrict__ xg, const float* __restrict__ Wg,
             const float* __restrict__ Ug, const float* __restrict__ bwg,
             const float* __restrict__ bug, float* __restrict__ out) {
  __shared__ float xl[2][4][16];    // x staging only (512 B)

  const int tid = threadIdx.x;
  const int row = tid >> 4;         // 0..3 = batch within wave
  const int i   = tid & 15;         // position within row
  const int b   = blockIdx.x * 4 + row;
  const int ux  = i;                // this lane's .x unit
  const int uy  = 16 + (i & 3);     // this lane's .y unit (4x replicated)

  constexpr float K1 = 1.44269504f; // log2(e)
  const float sg[4] = {-K1, -K1, -K1, 2.f * K1};
  const int M[16] = {0,1,2,3, 7,6,5,4, 15,14,13,12, 8,9,10,11};

  // Pre-scaled, butterfly-permuted weights. um[g][q] pairs with hx[q]
  // (unit k = i^M[q]); ue[g][q] pairs with hy[q] (unit 16+((i^q)&3)).
  f2 um[4][16], ue[4][4], wW[4], bb[4];
#pragma unroll
  for (int g = 0; g < 4; ++g) {
#pragma unroll
    for (int q = 0; q < 16; ++q) {
      const int k = i ^ M[q];
      um[g][q].x = Ug[(g * H + ux) * H + k] * sg[g];
      um[g][q].y = Ug[(g * H + uy) * H + k] * sg[g];
    }
#pragma unroll
    for (int q = 0; q < 4; ++q) {
      const int k = 16 + ((i ^ q) & 3);
      ue[g][q].x = Ug[(g * H + ux) * H + k] * sg[g];
      ue[g][q].y = Ug[(g * H + uy) * H + k] * sg[g];
    }
    wW[g].x = Wg[g * H + ux] * sg[g];
    wW[g].y = Wg[g * H + uy] * sg[g];
    bb[g].x = (bwg[g * H + ux] + bug[g * H + ux]) * sg[g];
    bb[g].y = (bwg[g * H + uy] + bug[g * H + uy]) * sg[g];
  }

  // Stage x chunk 0 (all 64 lanes: one slot each); prefetch chunk 1.
  xl[0][row][i] = xg[(size_t)i * B + b];
  float xnext = xg[(size_t)(CHUNK + i) * B + b];
  __builtin_amdgcn_wave_barrier();

  float hxv = 0.f, hyv = 0.f;       // h of unit ux / unit uy
  float cx = 0.f, cy = 0.f;         // c scaled by 2*log2e
  constexpr size_t OS = (size_t)B * H;
  float* outx = out + (size_t)b * H + ux;
  float* outy = out + (size_t)b * H + uy;

  for (int ch = 0; ch < NCH; ++ch) {
    const int cb = ch & 1;
    // Stage chunk ch+1 (held in xnext); prefetch chunk ch+2.
    xl[cb ^ 1][row][i] = xnext;
    { const int tp = (ch + 2) * CHUNK + i;
      xnext = (tp < T) ? xg[(size_t)tp * B + b] : 0.f; }
#pragma unroll
    for (int s = 0; s < CHUNK; ++s) {
      __builtin_amdgcn_wave_barrier();          // schedule pin (0 instr)
      // ---- register-only allgather (18 DPP movs, depth <=4) ----
      float hx[16], hy[4];
      hx[0] = hxv;
      hx[1] = dpp_f<0xB1>(hxv);
      hx[2] = dpp_f<0x4E>(hxv);
      hx[3] = dpp_f<0x4E>(hx[1]);
#pragma unroll
      for (int q = 0; q < 4; ++q) hx[4 + q] = dpp_f<0x141>(hx[q]);
#pragma unroll
      for (int q = 0; q < 8; ++q) hx[8 + q] = dpp_f<0x140>(hx[q]);
      hy[0] = hyv;
      hy[1] = dpp_f<0xB1>(hyv);
      hy[2] = dpp_f<0x4E>(hyv);
      hy[3] = dpp_f<0x4E>(hy[1]);
      const float xu = xl[cb][row][s];          // row-broadcast b32

      // ---- 4 gate chains (f2 = units ux,uy), 2 partials each ----
      f2 z[4];
#pragma unroll
      for (int g = 0; g < 4; ++g) {
        f2 pA = bb[g];
        f2 pB = wW[g] * dup(xu);
#pragma unroll
        for (int q = 0; q < 8; ++q)  pA = um[g][q] * dup(hx[q]) + pA;
#pragma unroll
        for (int q = 8; q < 16; ++q) pB = um[g][q] * dup(hx[q]) + pB;
#pragma unroll
        for (int q = 0; q < 4; ++q)  pB = ue[g][q] * dup(hy[q]) + pB;
        z[g] = pA + pB;
      }
      // ---- acts (r4-proven algebra), .x then .y ----
      {
        const float fg = rcp_f(1.f + ex2(z[0].x));
        const float ig = rcp_f(1.f + ex2(z[1].x));
        const float og = rcp_f(1.f + ex2(z[2].x));
        const float gt = fmaf(-2.f, rcp_f(1.f + ex2(z[3].x)), 1.f);
        cx = fmaf(fg, cx, (2.f * K1 * ig) * gt);
        const float r2 = rcp_f(1.f + ex2(cx));
        hxv = fmaf(-2.f * og, r2, og);
      }
      {
        const float fg = rcp_f(1.f + ex2(z[0].y));
        const float ig = rcp_f(1.f + ex2(z[1].y));
        const float og = rcp_f(1.f + ex2(z[2].y));
        const float gt = fmaf(-2.f, rcp_f(1.f + ex2(z[3].y)), 1.f);
        cy = fmaf(fg, cy, (2.f * K1 * ig) * gt);
        const float r2 = rcp_f(1.f + ex2(cy));
        hyv = fmaf(-2.f * og, r2, og);
      }
      *outx = hxv;                               // units 0..15
      if (i < 4) *outy = hyv;                    // units 16..19 (quad 0 only)
      outx += OS; outy += OS;
    }
  }

  out[OS * T + (size_t)b * H + ux] = hxv;                      // h_last
  out[OS * (T + 1) + (size_t)b * H + ux] = cx * 0.34657359f;   // c_last
  if (i < 4) {
    out[OS * T + (size_t)b * H + uy] = hyv;
    out[OS * (T + 1) + (size_t)b * H + uy] = cy * 0.34657359f;
  }
}

extern "C" void kernel_launch(void* const* d_in, const int* in_sizes, int n_in,
                              void* d_out, int out_size, void* d_ws, size_t ws_size,
                              hipStream_t stream) {
  (void)in_sizes; (void)n_in; (void)d_ws; (void)ws_size; (void)out_size;
  const float* x  = (const float*)d_in[0];
  const float* W  = (const float*)d_in[1];
  const float* U  = (const float*)d_in[2];
  const float* bw = (const float*)d_in[3];
  const float* bu = (const float*)d_in[4];
  float* out = (float*)d_out;

  lstm_qb<<<dim3(B / 4), dim3(64), 0, stream>>>(x, W, U, bw, bu, out);
}